// Round 6
// baseline (431623.633 us; speedup 1.0000x reference)
//
#include <hip/hip_runtime.h>

typedef signed char s8;   // activation flag: 1 = negative (-1), 0 = non-negative (+1)

#define L_X 16000
#define NB  64
#define P1  5320   // conv1(15960) pool3
#define P2  1746   // conv2(5240) pool3
#define P3  555    // conv3(1666) pool3
#define P4  158    // conv4(475) pool3
#define C5  78     // conv5 out (no pool)

__device__ __forceinline__ float frn_mul(float a, float b) { return __fmul_rn(a, b); }
__device__ __forceinline__ float frn_add(float a, float b) { return __fadd_rn(a, b); }

// ---- conv1: f32, k-outer array-accum, i-inner sequential; + scale_bias + sign + pool3 ----
// grid (P1, NB), block 64 = out channel
__global__ __launch_bounds__(64) void conv1_f(
        const float* __restrict__ x, const float* __restrict__ w1,
        const float* __restrict__ s0, const float* __restrict__ b0,
        const float* __restrict__ s1, const float* __restrict__ b1,
        s8* __restrict__ y1) {
    int q = blockIdx.x;
    int n = blockIdx.y;
    int co = threadIdx.x;
    float sq0[3], bb0[3];
    #pragma unroll
    for (int ci = 0; ci < 3; ++ci) {
        sq0[ci] = (s0[ci] < 0.f) ? -0.1f : 0.1f;   // bin_w(s0) = ±0.1f exactly
        bb0[ci] = b0[ci];
    }
    float sq1 = (s1[co] < 0.f) ? -0.1f : 0.1f;
    float bb1 = b1[co];
    bool neg = true;
    for (int r = 0; r < 3; ++r) {
        int p = 3 * q + r;
        float S = 0.f;
        for (int k = 0; k < 41; ++k) {
            float A = 0.f;
            #pragma unroll
            for (int ci = 0; ci < 3; ++ci) {
                float xv  = x[((size_t)n * 3 + ci) * L_X + p + k];
                float xsb = frn_add(frn_mul(xv, sq0[ci]), bb0[ci]);  // scale_bias, f32 once
                float wf  = (w1[((size_t)co * 3 + ci) * 41 + k] < 0.f) ? -0.1f : 0.1f;
                A = frn_add(A, frn_mul(xsb, wf));                    // sequential over i
            }
            S = frn_add(S, A);                                       // k-outer accumulate
        }
        float pre = frn_add(frn_mul(S, sq1), bb1);                   // scale_bias(s1,b1)
        neg = neg && (pre < 0.f);
    }
    y1[((size_t)n * 64 + co) * P1 + q] = neg ? 1 : 0;
}

// ---- binary conv (dilation 2), f32 sequential ±0.1f accumulation, same nesting ----
template <int CI, int POOLK>
__global__ void bconv_f(const s8* __restrict__ yin, const float* __restrict__ w,
                        const float* __restrict__ s, const float* __restrict__ b,
                        s8* __restrict__ yout, int Lin, int Lq) {
    int q = blockIdx.x;
    int n = blockIdx.y;
    int co = threadIdx.x;
    float sqf = (s[co] < 0.f) ? -0.1f : 0.1f;
    float bf = b[co];
    bool neg = true;
    for (int r = 0; r < POOLK; ++r) {
        int p = POOLK * q + r;
        float S = 0.f;
        for (int k = 0; k < 41; ++k) {
            float A = 0.f;
            for (int ci = 0; ci < CI; ++ci) {
                int aneg = yin[((size_t)n * CI + ci) * Lin + p + 2 * k];
                int wneg = (w[((size_t)co * CI + ci) * 41 + k] < 0.f) ? 1 : 0;
                A = frn_add(A, (aneg ^ wneg) ? -0.1f : 0.1f);  // ±1·(±0.1f) exact product
            }
            S = frn_add(S, A);
        }
        float pre = frn_add(frn_mul(S, sqf), bf);
        neg = neg && (pre < 0.f);
    }
    yout[((size_t)n * blockDim.x + co) * Lq + q] = neg ? 1 : 0;
}

// ---- fc1: sequential j accumulation of ±0.1f, + scale_bias + sign ----
__global__ void fc1_f(const s8* __restrict__ y5, const float* __restrict__ fw1,
                      const float* __restrict__ s6, const float* __restrict__ b6,
                      s8* __restrict__ y6) {
    int t = blockIdx.x * blockDim.x + threadIdx.x;
    if (t >= NB * 1024) return;
    int row = t & 1023;
    int n = t >> 10;
    const s8* yv = y5 + (size_t)n * 9984;
    const float* wv = fw1 + (size_t)row * 9984;
    float S = 0.f;
    for (int j = 0; j < 9984; ++j) {
        int aneg = yv[j];
        int wneg = (wv[j] < 0.f) ? 1 : 0;
        S = frn_add(S, (aneg ^ wneg) ? -0.1f : 0.1f);
    }
    float pre = frn_add(frn_mul(S, (s6[row] < 0.f) ? -0.1f : 0.1f), b6[row]);
    y6[t] = (pre < 0.f) ? 1 : 0;
}

// ---- fc2: sequential j, + scale_bias -> f32 out ----
__global__ void fc2_f(const s8* __restrict__ y6, const float* __restrict__ fw2,
                      const float* __restrict__ s7, const float* __restrict__ b7,
                      float* __restrict__ out) {
    int t = blockIdx.x * blockDim.x + threadIdx.x;
    if (t >= NB * 1000) return;
    int r = t % 1000;
    int n = t / 1000;
    const s8* yv = y6 + (size_t)n * 1024;
    const float* wv = fw2 + (size_t)r * 1024;
    float S = 0.f;
    for (int j = 0; j < 1024; ++j) {
        int aneg = yv[j];
        int wneg = (wv[j] < 0.f) ? 1 : 0;
        S = frn_add(S, (aneg ^ wneg) ? -0.1f : 0.1f);
    }
    out[t] = frn_add(frn_mul(S, (s7[r] < 0.f) ? -0.1f : 0.1f), b7[r]);
}

extern "C" void kernel_launch(void* const* d_in, const int* in_sizes, int n_in,
                              void* d_out, int out_size, void* d_ws, size_t ws_size,
                              hipStream_t stream) {
    const float* x   = (const float*)d_in[0];
    const float* s0  = (const float*)d_in[1];
    const float* b0  = (const float*)d_in[2];
    const float* w1  = (const float*)d_in[3];
    const float* s1  = (const float*)d_in[4];
    const float* b1  = (const float*)d_in[5];
    const float* w2  = (const float*)d_in[6];
    const float* s2  = (const float*)d_in[7];
    const float* b2  = (const float*)d_in[8];
    const float* w3  = (const float*)d_in[9];
    const float* s3  = (const float*)d_in[10];
    const float* b3  = (const float*)d_in[11];
    const float* w4  = (const float*)d_in[12];
    const float* s4  = (const float*)d_in[13];
    const float* b4  = (const float*)d_in[14];
    const float* w5  = (const float*)d_in[15];
    const float* s5  = (const float*)d_in[16];
    const float* b5  = (const float*)d_in[17];
    const float* fw1 = (const float*)d_in[18];
    const float* s6  = (const float*)d_in[19];
    const float* b6  = (const float*)d_in[20];
    const float* fw2 = (const float*)d_in[21];
    const float* s7  = (const float*)d_in[22];
    const float* b7  = (const float*)d_in[23];

    s8* p = (s8*)d_ws;
    s8* y1 = p; p += (size_t)NB * 64 * P1;
    s8* y2 = p; p += (size_t)NB * 64 * P2;
    s8* y3 = p; p += (size_t)NB * 128 * P3;
    s8* y4 = p; p += (size_t)NB * 128 * P4;
    s8* y5 = p; p += (size_t)NB * 128 * C5;
    s8* y6 = p; p += (size_t)NB * 1024;

    conv1_f<<<dim3(P1, NB), 64, 0, stream>>>(x, w1, s0, b0, s1, b1, y1);
    bconv_f<64, 3><<<dim3(P2, NB), 64, 0, stream>>>(y1, w2, s2, b2, y2, P1, P2);
    bconv_f<64, 3><<<dim3(P3, NB), 128, 0, stream>>>(y2, w3, s3, b3, y3, P2, P3);
    bconv_f<128, 3><<<dim3(P4, NB), 128, 0, stream>>>(y3, w4, s4, b4, y4, P3, P4);
    bconv_f<128, 1><<<dim3(C5, NB), 128, 0, stream>>>(y4, w5, s5, b5, y5, P4, C5);
    fc1_f<<<(NB * 1024 + 255) / 256, 256, 0, stream>>>(y5, fw1, s6, b6, y6);
    fc2_f<<<(NB * 1000 + 255) / 256, 256, 0, stream>>>(y6, fw2, s7, b7, (float*)d_out);
}

// Round 7
// 7942.150 us; speedup vs baseline: 54.3459x; 54.3459x over previous
//
#include <hip/hip_runtime.h>
#include <cstdint>

typedef unsigned long long u64;
typedef unsigned int u32;

#define L_X 16000
#define NB  64
#define P1  5320   // conv1(15960) pool3
#define P2  1746   // conv2(5240) pool3
#define P3  555    // conv3(1666) pool3
#define P4  158    // conv4(475) pool3
#define C5  78     // conv5 out (no pool)

// exact bf-chain step helper: A = fl(A + (bit ? -0.1f : +0.1f)) for 64 bits LSB-first
__device__ __forceinline__ void chain64(float& A, u64 u) {
    u32 wlo = (u32)u, whi = (u32)(u >> 32);
    #pragma unroll
    for (int j = 0; j < 32; ++j)
        A = __fadd_rn(A, __uint_as_float(0x3DCCCCCDu | ((wlo << (31 - j)) & 0x80000000u)));
    #pragma unroll
    for (int j = 0; j < 32; ++j)
        A = __fadd_rn(A, __uint_as_float(0x3DCCCCCDu | ((whi << (31 - j)) & 0x80000000u)));
}

// ---------------- packing kernels ----------------
// conv1 weights -> transposed signed floats: w1T[(ci*41+k)*64 + co] = +-0.1f
__global__ void pack_w1T(const float* __restrict__ w1, float* __restrict__ w1T) {
    int t = blockIdx.x * blockDim.x + threadIdx.x;
    if (t >= 3 * 41 * 64) return;
    int co = t & 63;
    int rem = t >> 6;
    int k = rem % 41;
    int ci = rem / 41;
    w1T[t] = (w1[((size_t)co * 3 + ci) * 41 + k] < 0.f) ? -0.1f : 0.1f;
}

// conv weights (Co, CI=CIW*64, 41) -> bit words wT[(k*CIW+h)*Co + co], bit c = w<0
__global__ void pack_wT(const float* __restrict__ w, u64* __restrict__ wT,
                        int Co, int CIW) {
    int t = blockIdx.x * blockDim.x + threadIdx.x;
    if (t >= Co * 41 * CIW) return;
    int co = t % Co;
    int rem = t / Co;
    int h = rem % CIW;
    int k = rem / CIW;
    int CI = CIW * 64;
    u64 word = 0;
    for (int c = 0; c < 64; ++c)
        if (w[((size_t)co * CI + h * 64 + c) * 41 + k] < 0.f) word |= 1ull << c;
    wT[t] = word;
}

// fw1 (1024, 9984) -> fw1T[j*1024 + row], bit c = fw1[row*9984 + j*64 + c] < 0
__global__ void pack_fw1T(const float* __restrict__ w, u64* __restrict__ wT) {
    int t = blockIdx.x * blockDim.x + threadIdx.x;
    if (t >= 156 * 1024) return;
    int row = t & 1023;
    int j = t >> 10;
    const float* base = w + (size_t)row * 9984 + j * 64;
    u64 word = 0;
    for (int c = 0; c < 64; ++c)
        if (base[c] < 0.f) word |= 1ull << c;
    wT[t] = word;
}

// fw2 (1000, 1024) -> fw2T[j*1000 + row], bit c = fw2[row*1024 + j*64 + c] < 0
__global__ void pack_fw2T(const float* __restrict__ w, u64* __restrict__ wT) {
    int t = blockIdx.x * blockDim.x + threadIdx.x;
    if (t >= 16 * 1000) return;
    int row = t % 1000;
    int j = t / 1000;
    const float* base = w + (size_t)row * 1024 + j * 64;
    u64 word = 0;
    for (int c = 0; c < 64; ++c)
        if (base[c] < 0.f) word |= 1ull << c;
    wT[t] = word;
}

// repack conv5 channel-major bits into fc1 flat-reshape order:
// a5F[n*156 + j] bit c <-> flat jj = j*64+c, jj = chan*78 + tpos
__global__ void repack_a5(const u64* __restrict__ a5, u64* __restrict__ a5F) {
    int t = blockIdx.x * blockDim.x + threadIdx.x;
    if (t >= NB * 156) return;
    int j = t % 156;
    int n = t / 156;
    u64 word = 0;
    #pragma unroll
    for (int c = 0; c < 64; ++c) {
        int jj = j * 64 + c;
        int chan = jj / 78;
        int tp = jj - chan * 78;
        u64 src = a5[((size_t)n * C5 + tp) * 2 + (chan >> 6)];
        word |= ((src >> (chan & 63)) & 1ull) << c;
    }
    a5F[t] = word;
}

// ---------------- conv1 + scale_bias + sign + pool3 ----------------
// grid (P1, NB), block 64 = out channel; output bit word per (n,q)
__global__ __launch_bounds__(64) void conv1_k(
        const float* __restrict__ x, const float* __restrict__ w1T,
        const float* __restrict__ s0, const float* __restrict__ b0,
        const float* __restrict__ s1, const float* __restrict__ b1,
        u64* __restrict__ a1) {
    int q = blockIdx.x;
    int n = blockIdx.y;
    int co = threadIdx.x;
    float sq0[3], bb0[3];
    #pragma unroll
    for (int ci = 0; ci < 3; ++ci) {
        sq0[ci] = (s0[ci] < 0.f) ? -0.1f : 0.1f;
        bb0[ci] = b0[ci];
    }
    float sq1 = (s1[co] < 0.f) ? -0.1f : 0.1f;
    float bb1 = b1[co];
    bool neg = true;
    for (int r = 0; r < 3; ++r) {
        int p = 3 * q + r;
        float S = 0.f;
        #pragma unroll 1
        for (int k = 0; k < 41; ++k) {
            float A = 0.f;
            #pragma unroll
            for (int ci = 0; ci < 3; ++ci) {
                float xv  = x[((size_t)n * 3 + ci) * L_X + p + k];
                float xsb = __fadd_rn(__fmul_rn(xv, sq0[ci]), bb0[ci]);
                float wf  = w1T[(ci * 41 + k) * 64 + co];
                A = __fadd_rn(A, __fmul_rn(xsb, wf));
            }
            S = __fadd_rn(S, A);
        }
        float pre = __fadd_rn(__fmul_rn(S, sq1), bb1);
        neg = neg && (pre < 0.f);
    }
    u64 word = __ballot(neg);
    if (co == 0) a1[(size_t)n * P1 + q] = word;
}

// ---------------- binary conv (bit chain) + scale_bias + sign (+pool) ----------------
// block = Co threads; grid (Lq, NB). abits_in: [(n*Lin + pos)*CIW + h]
template <int CIW, int POOLK>
__global__ void bconv_k(const u64* __restrict__ abits_in, const u64* __restrict__ wT,
                        const float* __restrict__ s, const float* __restrict__ b,
                        u64* __restrict__ abits_out, int Lin, int Lq) {
    int q = blockIdx.x;
    int n = blockIdx.y;
    int co = threadIdx.x;
    int Co = blockDim.x;
    int wave = co >> 6;
    int CoW = Co >> 6;
    float sqf = (s[co] < 0.f) ? -0.1f : 0.1f;
    float bf = b[co];
    bool neg = true;
    for (int r = 0; r < POOLK; ++r) {
        int p = POOLK * q + r;
        float S = 0.f;
        #pragma unroll 1
        for (int k = 0; k < 41; ++k) {
            float A = 0.f;
            #pragma unroll
            for (int h = 0; h < CIW; ++h) {
                u64 u = abits_in[((size_t)n * Lin + p + 2 * k) * CIW + h]
                      ^ wT[(k * CIW + h) * Co + co];
                chain64(A, u);
            }
            S = __fadd_rn(S, A);
        }
        float pre = __fadd_rn(__fmul_rn(S, sqf), bf);
        neg = neg && (pre < 0.f);
    }
    u64 word = __ballot(neg);
    if ((co & 63) == 0) abits_out[((size_t)n * Lq + q) * CoW + wave] = word;
}

// ---------------- fc1: single sequential chain over 9984 bits ----------------
// grid (16, NB), block 64; lane -> row = g*64+lane
__global__ __launch_bounds__(64) void fc1_k(
        const u64* __restrict__ a5F, const u64* __restrict__ fw1T,
        const float* __restrict__ s6, const float* __restrict__ b6,
        u64* __restrict__ y6b) {
    int g = blockIdx.x;
    int n = blockIdx.y;
    int lane = threadIdx.x;
    int row = g * 64 + lane;
    float S = 0.f;
    #pragma unroll 1
    for (int j = 0; j < 156; ++j) {
        u64 u = a5F[(size_t)n * 156 + j] ^ fw1T[(size_t)j * 1024 + row];
        chain64(S, u);
    }
    float pre = __fadd_rn(__fmul_rn(S, (s6[row] < 0.f) ? -0.1f : 0.1f), b6[row]);
    u64 word = __ballot(pre < 0.f);
    if (lane == 0) y6b[n * 16 + g] = word;
}

// ---------------- fc2: single chain over 1024 bits -> f32 out ----------------
__global__ void fc2_k(const u64* __restrict__ y6b, const u64* __restrict__ fw2T,
                      const float* __restrict__ s7, const float* __restrict__ b7,
                      float* __restrict__ out) {
    int t = blockIdx.x * blockDim.x + threadIdx.x;
    if (t >= NB * 1000) return;
    int r = t % 1000;
    int n = t / 1000;
    float S = 0.f;
    #pragma unroll 1
    for (int j = 0; j < 16; ++j) {
        u64 u = y6b[n * 16 + j] ^ fw2T[j * 1000 + r];
        chain64(S, u);
    }
    out[t] = __fadd_rn(__fmul_rn(S, (s7[r] < 0.f) ? -0.1f : 0.1f), b7[r]);
}

// ---------------- launch ----------------
extern "C" void kernel_launch(void* const* d_in, const int* in_sizes, int n_in,
                              void* d_out, int out_size, void* d_ws, size_t ws_size,
                              hipStream_t stream) {
    const float* x   = (const float*)d_in[0];
    const float* s0  = (const float*)d_in[1];
    const float* b0  = (const float*)d_in[2];
    const float* w1  = (const float*)d_in[3];
    const float* s1  = (const float*)d_in[4];
    const float* b1  = (const float*)d_in[5];
    const float* w2  = (const float*)d_in[6];
    const float* s2  = (const float*)d_in[7];
    const float* b2  = (const float*)d_in[8];
    const float* w3  = (const float*)d_in[9];
    const float* s3  = (const float*)d_in[10];
    const float* b3  = (const float*)d_in[11];
    const float* w4  = (const float*)d_in[12];
    const float* s4  = (const float*)d_in[13];
    const float* b4  = (const float*)d_in[14];
    const float* w5  = (const float*)d_in[15];
    const float* s5  = (const float*)d_in[16];
    const float* b5  = (const float*)d_in[17];
    const float* fw1 = (const float*)d_in[18];
    const float* s6  = (const float*)d_in[19];
    const float* b6  = (const float*)d_in[20];
    const float* fw2 = (const float*)d_in[21];
    const float* s7  = (const float*)d_in[22];
    const float* b7  = (const float*)d_in[23];

    u64* p = (u64*)d_ws;
    float* w1T = (float*)p; p += 3936;          // 3*41*64 floats
    u64* w2T  = p; p += 41 * 64;
    u64* w3T  = p; p += 41 * 128;
    u64* w4T  = p; p += 82 * 128;
    u64* w5T  = p; p += 82 * 128;
    u64* fw1T = p; p += 156 * 1024;
    u64* fw2T = p; p += 16 * 1000;
    u64* a1   = p; p += (size_t)NB * P1;
    u64* a2   = p; p += (size_t)NB * P2;
    u64* a3   = p; p += (size_t)NB * P3 * 2;
    u64* a4   = p; p += (size_t)NB * P4 * 2;
    u64* a5   = p; p += (size_t)NB * C5 * 2;
    u64* a5F  = p; p += (size_t)NB * 156;
    u64* y6b  = p; p += (size_t)NB * 16;

    pack_w1T<<<(3 * 41 * 64 + 255) / 256, 256, 0, stream>>>(w1, w1T);
    pack_wT<<<(64 * 41 + 255) / 256, 256, 0, stream>>>(w2, w2T, 64, 1);
    pack_wT<<<(128 * 41 + 255) / 256, 256, 0, stream>>>(w3, w3T, 128, 1);
    pack_wT<<<(128 * 82 + 255) / 256, 256, 0, stream>>>(w4, w4T, 128, 2);
    pack_wT<<<(128 * 82 + 255) / 256, 256, 0, stream>>>(w5, w5T, 128, 2);
    pack_fw1T<<<(156 * 1024 + 255) / 256, 256, 0, stream>>>(fw1, fw1T);
    pack_fw2T<<<(16 * 1000 + 255) / 256, 256, 0, stream>>>(fw2, fw2T);

    conv1_k<<<dim3(P1, NB), 64, 0, stream>>>(x, w1T, s0, b0, s1, b1, a1);
    bconv_k<1, 3><<<dim3(P2, NB), 64, 0, stream>>>(a1, w2T, s2, b2, a2, P1, P2);
    bconv_k<1, 3><<<dim3(P3, NB), 128, 0, stream>>>(a2, w3T, s3, b3, a3, P2, P3);
    bconv_k<2, 3><<<dim3(P4, NB), 128, 0, stream>>>(a3, w4T, s4, b4, a4, P3, P4);
    bconv_k<2, 1><<<dim3(C5, NB), 128, 0, stream>>>(a4, w5T, s5, b5, a5, P4, C5);
    repack_a5<<<(NB * 156 + 255) / 256, 256, 0, stream>>>(a5, a5F);
    fc1_k<<<dim3(16, NB), 64, 0, stream>>>(a5F, fw1T, s6, b6, y6b);
    fc2_k<<<(NB * 1000 + 255) / 256, 256, 0, stream>>>(y6b, fw2T, s7, b7, (float*)d_out);
}